// Round 11
// baseline (2024.987 us; speedup 1.0000x reference)
//
#include <hip/hip_runtime.h>
#include <hip/hip_bf16.h>

typedef __attribute__((ext_vector_type(8))) short s16x8;
typedef __attribute__((ext_vector_type(4))) float f32x4;
typedef unsigned long long u64;

__device__ __forceinline__ ushort f2bf(float x) {
  __hip_bfloat16 b = __float2bfloat16(x);
  return *reinterpret_cast<ushort*>(&b);
}
__device__ __forceinline__ float bf2f(ushort u) {
  union { unsigned int i; float f; } c; c.i = ((unsigned int)u) << 16; return c.f;
}
__device__ __forceinline__ float sigm_fast(float z) {
  return __builtin_amdgcn_rcpf(1.0f + __builtin_amdgcn_exp2f(z * -1.44269504088896f));
}
__device__ __forceinline__ u64 aload(const u64* p) {
  return __hip_atomic_load(p, __ATOMIC_RELAXED, __HIP_MEMORY_SCOPE_AGENT);
}

// ---------------------------------------------------------------------------
// K0: pack weights (validated R1-R10).
// ---------------------------------------------------------------------------
__global__ __launch_bounds__(256) void pack_weights(
    const float* __restrict__ Wf, const float* __restrict__ Wi,
    const float* __restrict__ Wg, const float* __restrict__ Wo,
    const float* __restrict__ Rf, const float* __restrict__ Ri,
    const float* __restrict__ Rg, const float* __restrict__ Ro,
    const float* __restrict__ bfp, const float* __restrict__ bip,
    const float* __restrict__ bgp, const float* __restrict__ bop,
    ushort* __restrict__ Wx, ushort* __restrict__ Rs, float* __restrict__ bp)
{
  const int p = blockIdx.x * 8 + (threadIdx.x >> 5);
  const int kk = (threadIdx.x & 31) * 16;
  const int gate = p & 3;
  const int hcol = (p >> 5) * 8 + ((p >> 4) & 1) * 4 + ((p & 15) >> 2);
  const float* W = (gate == 0) ? Wf : (gate == 1) ? Wi : (gate == 2) ? Wg : Wo;
  const float* R = (gate == 0) ? Rf : (gate == 1) ? Ri : (gate == 2) ? Rg : Ro;
  union { ushort u[16]; s16x8 v[2]; } wb, rb;
#pragma unroll
  for (int e = 0; e < 16; ++e) {
    const int k = kk + e;
    wb.u[e] = f2bf(W[(size_t)k * 512 + hcol]);
    rb.u[e] = f2bf(W[(size_t)(512 + k) * 512 + hcol] + R[(size_t)k * 512 + hcol]);
  }
  *(s16x8*)(Wx + (size_t)p * 512 + kk)     = wb.v[0];
  *(s16x8*)(Wx + (size_t)p * 512 + kk + 8) = wb.v[1];
  *(s16x8*)(Rs + (size_t)p * 512 + kk)     = rb.v[0];
  *(s16x8*)(Rs + (size_t)p * 512 + kk + 8) = rb.v[1];
  if ((threadIdx.x & 31) == 0) {
    const float* B = (gate == 0) ? bfp : (gate == 1) ? bip : (gate == 2) ? bgp : bop;
    bp[p] = B[hcol];
  }
}

// ---------------------------------------------------------------------------
// Fused kernel: grid = 192 WGs x 512 thr.
//   bid <  64: recurrence slots. Active iff (bid&7) < 4: g = bid&7, mem =
//     bid>>3 — under round-robin blockIdx->XCD, ALL 8 members of group g sit
//     on XCD g, so workgroup-scope (plain) stores land dirty in the SHARED
//     per-XCD L2 and consumers' agent loads hit-forward there (~5x cheaper
//     than MALL). Producer dual-stores each tagged chunk (plain -> L2, then
//     agent -> MALL) so wrong mapping / no hit-forward degrades to R10
//     behavior instead of hanging. Tags = readiness (no flags, no vmcnt).
//   bid >= 64: Zx GEMM for chunk [zxt0, zxt0+CH) -> zxw (bf16), 128 WGs.
// hbc layout: u64 [slot][g][mem][384]; member chunk = [row16][span4][k6].
// ---------------------------------------------------------------------------
__global__ __launch_bounds__(512, 1) void fused_kernel(
    const float* __restrict__ x, const ushort* __restrict__ Wx,
    const ushort* __restrict__ Rs, const float* __restrict__ bp,
    const ushort* __restrict__ zxr, ushort* __restrict__ zxw,
    u64* __restrict__ hbc, float* __restrict__ csave,
    ushort* __restrict__ hsave, float* __restrict__ cfinal,
    int t0, int CH, int zxt0, int do_rec)
{
  __shared__ ushort lds_u[33280];  // zx: [64][520]; rec: hsl(8192)+tbuf(1024)
  const int tid = threadIdx.x;
  const int wid = tid >> 6;
  const int lane = tid & 63;
  const int l15 = lane & 15;
  const int hi = lane >> 4;

  if (blockIdx.x >= 64) {
    // ================= Zx GEMM path (validated R5-R10) =================
    if (zxt0 >= 512) return;
    const int zbid = blockIdx.x - 64;
    const int pg = zbid & 15;
    const int ts = zbid >> 4;
    const int mpair = wid >> 2;
    const int np = wid & 3;
    const int q = pg * 4 + np;
    s16x8 Bg[2][16];
#pragma unroll
    for (int nt = 0; nt < 2; ++nt)
#pragma unroll
      for (int kc = 0; kc < 16; ++kc)
        Bg[nt][kc] = *(const s16x8*)(Wx + (size_t)(q * 32 + nt * 16 + l15) * 512 + kc * 32 + hi * 8);
    const int tper = CH >> 3;
    for (int tt = 0; tt < tper; ++tt) {
      const int tl = ts * tper + tt;
      const int t = zxt0 + tl;
      const float4* x4 = (const float4*)(x + (size_t)t * 32768);
#pragma unroll
      for (int j = 0; j < 16; ++j) {
        const int i4 = j * 512 + tid;
        const float4 v = x4[i4];
        const int row = i4 >> 7;
        const int c0 = (i4 & 127) * 4;
        ushort4 u;
        u.x = f2bf(v.x); u.y = f2bf(v.y); u.z = f2bf(v.z); u.w = f2bf(v.w);
        *(ushort4*)(&lds_u[row * 520 + c0]) = u;
      }
      __syncthreads();
#pragma unroll
      for (int a = 0; a < 2; ++a) {
        const int mt = mpair * 2 + a;
        f32x4 a0 = {0.f, 0.f, 0.f, 0.f};
        f32x4 a1 = {0.f, 0.f, 0.f, 0.f};
#pragma unroll
        for (int kc = 0; kc < 16; ++kc) {
          const s16x8 af = *(const s16x8*)(&lds_u[(mt * 16 + l15) * 520 + kc * 32 + hi * 8]);
          a0 = __builtin_amdgcn_mfma_f32_16x16x32_bf16(af, Bg[0][kc], a0, 0, 0, 0);
          a1 = __builtin_amdgcn_mfma_f32_16x16x32_bf16(af, Bg[1][kc], a1, 0, 0, 0);
        }
        union { ushort u[8]; s16x8 v; } ub;
#pragma unroll
        for (int r = 0; r < 4; ++r) { ub.u[r] = f2bf(a0[r]); ub.u[4 + r] = f2bf(a1[r]); }
        *(s16x8*)(zxw + ((((size_t)tl * 4 + mt) * 64 + q) * 64 + lane) * 8) = ub.v;
      }
      __syncthreads();
    }
    return;
  }

  // ================= recurrence path =================
  const int bid = blockIdx.x;
  if ((bid & 7) >= 4) return;    // dead slots: align groups to XCD residues
  if (!do_rec) return;
  ushort* hsl = lds_u;           // 8192 ushorts, swizzled h tile
  ushort* tbuf = lds_u + 8192;   // 1024 ushorts, publish transpose
  const int g = bid & 7;         // group 0..3 == XCD residue (round-robin)
  const int mem = bid >> 3;      // member 0..7 (same residue -> same XCD)
  const int q = mem * 8 + wid;   // packed col-group 0..63
  const int gate = lane & 3;

  // Rsum fragments (parked in AGPRs by the compiler; MFMA reads them directly)
  f32x4 Brg[2][16];
#pragma unroll
  for (int nt = 0; nt < 2; ++nt)
#pragma unroll
    for (int kc = 0; kc < 16; ++kc) {
      Brg[nt][kc] = *(const f32x4*)(Rs + (size_t)(q * 32 + nt * 16 + l15) * 512 + kc * 32 + hi * 8);
      asm volatile("" : "+v"(Brg[nt][kc]));
    }
  const float b0 = bp[q * 32 + l15];
  const float b1 = bp[q * 32 + 16 + l15];

  float cst[2][4];
  float* csp = csave + ((size_t)((g * 8 + mem) * 8 + wid) * 64 + lane) * 8;
  if (t0 == 0) {
#pragma unroll
    for (int i = 0; i < 2; ++i)
#pragma unroll
      for (int r = 0; r < 4; ++r) cst[i][r] = 0.0f;
  } else {
#pragma unroll
    for (int i = 0; i < 2; ++i)
#pragma unroll
      for (int r = 0; r < 4; ++r) cst[i][r] = csp[i * 4 + r];
  }

  const int srow = hi * 4 + gate;
  // consumer constants: thread stages row crow, cols [c0, c0+16)
  const int crow = tid >> 5;
  const int c0 = (tid & 31) * 16;
  const int memr = c0 >> 6;
  const int q0c = (crow * 4 + ((c0 & 63) >> 4)) * 6;
  const int cbyte = (tid & 31) * 32;
  const int cswz = (crow & 7) << 4;
  const int wofs0 = (crow * 1024 + (cbyte ^ cswz)) >> 1;
  const int wofs1 = (crow * 1024 + ((cbyte + 16) ^ cswz)) >> 1;
  const int abase = l15 * 1024 + hi * 16;
  const int aswz = (l15 & 7) << 4;
  // producer constants (chunk tid < 384): [row 16][span 4][k 6]
  const int prow = tid / 24;
  const int pspan = (tid / 6) & 3;
  const int pk = tid - (tid / 6) * 6;
  const int mc0p = pspan * 16 + pk * 3;
  const int mc1p = (mc0p + 1 < (pspan + 1) * 16) ? mc0p + 1 : mc0p;
  const int mc2p = (mc0p + 2 < (pspan + 1) * 16) ? mc0p + 2 : mc0p;
  const int tb0 = ((mc0p >> 3) & 7) * 128 + prow * 8 + (mc0p & 7);
  const int tb1 = ((mc1p >> 3) & 7) * 128 + prow * 8 + (mc1p & 7);
  const int tb2 = ((mc2p >> 3) & 7) * 128 + prow * 8 + (mc2p & 7);

  for (int tl = 0; tl < CH; ++tl) {
    const int t = t0 + tl;
    const ushort tau = (ushort)t;
    // zx prefetch (independent; flies during validate)
    const s16x8 zv = *(const s16x8*)(zxr + ((((size_t)tl * 4 + g) * 64 + q) * 64 + lane) * 8);
    // --- tagged chunk load + validate: readiness and data in one round ---
    u64 chv[6];
    {
      const u64* vb = hbc + (((size_t)tl * 4 + g) * 8 + memr) * 384 + q0c;
#pragma unroll
      for (int i = 0; i < 6; ++i) chv[i] = aload(vb + i);
      int rounds = 0;
      for (;;) {
        int ok = 1;
#pragma unroll
        for (int i = 0; i < 6; ++i)
          if ((ushort)(chv[i] >> 48) != tau) { chv[i] = aload(vb + i); ok = 0; }
        if (ok) break;
        if (++rounds > 8) __builtin_amdgcn_s_sleep(1);
      }
      asm volatile("" ::: "memory");
    }
    // --- unpack 16 values -> hsl (swizzled) ---
    union { ushort u[8]; s16x8 v; } ha, hb2;
#pragma unroll
    for (int j = 0; j < 8; ++j)  ha.u[j]      = (ushort)(chv[j / 3] >> (16 * (j % 3)));
#pragma unroll
    for (int j = 8; j < 16; ++j) hb2.u[j - 8] = (ushort)(chv[j / 3] >> (16 * (j % 3)));
    *(s16x8*)(&hsl[wofs0]) = ha.v;
    *(s16x8*)(&hsl[wofs1]) = hb2.v;
    asm volatile("s_waitcnt lgkmcnt(0)" ::: "memory");
    __builtin_amdgcn_s_barrier();           // bar1: hsl staged (no vmem drain)
    asm volatile("" ::: "memory");
    // --- z = h @ Rsum ---
    f32x4 a0 = {0.f, 0.f, 0.f, 0.f};
    f32x4 a1 = {0.f, 0.f, 0.f, 0.f};
#pragma unroll
    for (int kc = 0; kc < 16; ++kc) {
      const s16x8 af = *(const s16x8*)(&hsl[((abase + kc * 64) ^ aswz) >> 1]);
      a0 = __builtin_amdgcn_mfma_f32_16x16x32_bf16(af, __builtin_bit_cast(s16x8, Brg[0][kc]), a0, 0, 0, 0);
      a1 = __builtin_amdgcn_mfma_f32_16x16x32_bf16(af, __builtin_bit_cast(s16x8, Brg[1][kc]), a1, 0, 0, 0);
    }
    // --- gates + cell update ---
    float hv[2], cv[2];
#pragma unroll
    for (int nt = 0; nt < 2; ++nt) {
      float hr[4];
#pragma unroll
      for (int r = 0; r < 4; ++r) {
        float z = (nt ? a1[r] : a0[r]) + bf2f((ushort)zv[nt * 4 + r]) + (nt ? b1 : b0);
        const float zz = (gate == 2) ? z + z : z;
        const float s = sigm_fast(zz);
        const float act = (gate == 2) ? (s + s - 1.0f) : s;
        const int ai = __float_as_int(act);
        const float fv = __int_as_float(__builtin_amdgcn_mov_dpp(ai, 0x00, 0xF, 0xF, true));
        const float iv = __int_as_float(__builtin_amdgcn_mov_dpp(ai, 0x55, 0xF, 0xF, true));
        const float gv = __int_as_float(__builtin_amdgcn_mov_dpp(ai, 0xAA, 0xF, 0xF, true));
        const float ov = __int_as_float(__builtin_amdgcn_mov_dpp(ai, 0xFF, 0xF, 0xF, true));
        const float cn = fmaf(fv, cst[nt][r], iv * gv);
        cst[nt][r] = cn;
        const float s2 = sigm_fast(cn + cn);
        hr[r] = ov * (s2 + s2 - 1.0f);
      }
      hv[nt] = (gate == 0) ? hr[0] : (gate == 1) ? hr[1] : (gate == 2) ? hr[2] : hr[3];
      cv[nt] = (gate == 0) ? cst[nt][0] : (gate == 1) ? cst[nt][1]
             : (gate == 2) ? cst[nt][2] : cst[nt][3];
    }
    const ushort pb0 = f2bf(hv[0]), pb1 = f2bf(hv[1]);
    // --- h archive (fire-and-forget) ---
    {
      ushort2 hp; hp.x = pb0; hp.y = pb1;
      *(ushort2*)(hsave + (((size_t)t * 4 + g) * 8 + mem) * 1024 + wid * 128 + lane * 2) = hp;
      if (t == 511) {
        float* cf = cfinal + (((size_t)(g * 8 + mem) * 8 + wid) * 64 + lane) * 2;
        cf[0] = cv[0]; cf[1] = cv[1];
      }
    }
    // --- tbuf transpose fill ---
    tbuf[wid * 128 + srow * 8 + (l15 >> 2)]     = pb0;
    tbuf[wid * 128 + srow * 8 + (l15 >> 2) + 4] = pb1;
    asm volatile("s_waitcnt lgkmcnt(0)" ::: "memory");
    __builtin_amdgcn_s_barrier();           // bar2: tbuf complete (no vmem drain)
    asm volatile("" ::: "memory");
    // --- gather + DUAL-issue tagged chunk stores (slot tl+1; wraps to 0) ---
    // plain/workgroup store -> dirty line in this XCD's shared L2 (fast path
    // for same-XCD consumers); agent store (same value) -> MALL (progress
    // guarantee for any consumer). Same addr+value => order-immune.
    if (tid < 384) {
      const ushort v0p = tbuf[tb0];
      const ushort v1p = tbuf[tb1];
      const ushort v2p = tbuf[tb2];
      const u64 pk64 = (u64)v0p | ((u64)v1p << 16) | ((u64)v2p << 32)
                     | ((u64)(ushort)(t + 1) << 48);
      const int dsl = (tl + 1 < CH) ? (tl + 1) : 0;
      u64* dst = hbc + (((size_t)dsl * 4 + g) * 8 + mem) * 384 + tid;
      __hip_atomic_store(dst, pk64, __ATOMIC_RELAXED, __HIP_MEMORY_SCOPE_WORKGROUP);
      asm volatile("" ::: "memory");  // keep both stores (no merge-elimination)
      __hip_atomic_store(dst, pk64, __ATOMIC_RELAXED, __HIP_MEMORY_SCOPE_AGENT);
    }
    __builtin_amdgcn_s_barrier();           // bar3: all waves' stores issued
    asm volatile("" ::: "memory");
  }
#pragma unroll
  for (int i = 0; i < 2; ++i)
#pragma unroll
    for (int r = 0; r < 4; ++r) csp[i * 4 + r] = cst[i][r];
}

// ---------------------------------------------------------------------------
// Reorder: hsave/cfinal -> dout (validated R5-R10).
// ---------------------------------------------------------------------------
__global__ __launch_bounds__(256) void reorder_kernel(
    const ushort* __restrict__ hsave, const float* __restrict__ cfinal,
    float* __restrict__ dout)
{
  __shared__ ushort lds[8192];
  const int t = blockIdx.x;
  const int g = blockIdx.y;
  const int tid = threadIdx.x;
  const s16x8* src = (const s16x8*)(hsave + ((size_t)t * 4 + g) * 8192);
#pragma unroll
  for (int j = 0; j < 4; ++j) {
    const int i = j * 256 + tid;
    *(s16x8*)(&lds[i * 8]) = src[i];
  }
  __syncthreads();
  const int srow = tid >> 4;
  const int cb = (tid & 15) * 32;
  float buf[32];
#pragma unroll
  for (int cc = 0; cc < 32; ++cc) {
    const int col = cb + cc;
    const int q = col >> 3;
    const int memb = q >> 3;
    const int wd = q & 7;
    const int nt = (col >> 2) & 1;
    const int l15v = ((col & 3) << 2) | (srow & 3);
    const int lanev = ((srow >> 2) << 4) | l15v;
    buf[cc] = bf2f(lds[memb * 1024 + wd * 128 + lanev * 2 + nt]);
  }
  float* o = dout + (size_t)t * 32768 + (size_t)(g * 16 + srow) * 512 + cb;
#pragma unroll
  for (int j = 0; j < 8; ++j) *(float4*)(o + j * 4) = *(const float4*)(&buf[j * 4]);
  if (t == 511) {
    float* oh = dout + (size_t)16777216 + (size_t)(g * 16 + srow) * 512 + cb;
#pragma unroll
    for (int j = 0; j < 8; ++j) *(float4*)(oh + j * 4) = *(const float4*)(&buf[j * 4]);
    float cbuf[32];
#pragma unroll
    for (int cc = 0; cc < 32; ++cc) {
      const int col = cb + cc;
      const int q = col >> 3;
      const int memb = q >> 3;
      const int wd = q & 7;
      const int nt = (col >> 2) & 1;
      const int l15v = ((col & 3) << 2) | (srow & 3);
      const int lanev = ((srow >> 2) << 4) | l15v;
      cbuf[cc] = cfinal[(((size_t)(g * 8 + memb) * 8 + wd) * 64 + lanev) * 2 + nt];
    }
    float* oc = dout + (size_t)16809984 + (size_t)(g * 16 + srow) * 512 + cb;
#pragma unroll
    for (int j = 0; j < 8; ++j) *(float4*)(oc + j * 4) = *(const float4*)(&cbuf[j * 4]);
  }
}

// ---------------------------------------------------------------------------
extern "C" void kernel_launch(void* const* d_in, const int* in_sizes, int n_in,
                              void* d_out, int out_size, void* d_ws, size_t ws_size,
                              hipStream_t stream)
{
  const float* x   = (const float*)d_in[0];
  const float* Wf  = (const float*)d_in[1];
  const float* bfp = (const float*)d_in[2];
  const float* Wi  = (const float*)d_in[3];
  const float* bip = (const float*)d_in[4];
  const float* Wg  = (const float*)d_in[5];
  const float* bgp = (const float*)d_in[6];
  const float* Wo  = (const float*)d_in[7];
  const float* bop = (const float*)d_in[8];
  const float* Rf  = (const float*)d_in[9];
  const float* Ri  = (const float*)d_in[10];
  const float* Rg  = (const float*)d_in[11];
  const float* Ro  = (const float*)d_in[12];
  float* dout = (float*)d_out;
  char* ws = (char*)d_ws;

  const size_t o_Wx = 0;
  const size_t o_Rs = 2097152;
  const size_t o_bp = 4194304;
  const size_t o_z0 = o_bp + 8192;

  int CH = 64;
  for (;;) {
    const size_t need = o_z0 + 2 * (size_t)CH * 262144   // zx double buffer
                      + (size_t)CH * 98304               // hbc tagged chunks
                      + 524288                           // csave
                      + 33554432 + 131072;               // hsave, cfinal
    if (need <= ws_size || CH <= 8) break;
    CH >>= 1;
  }
  const size_t zsz   = (size_t)CH * 262144;
  const size_t o_z1  = o_z0 + zsz;
  const size_t o_hbc = o_z1 + zsz;
  const size_t o_cs  = o_hbc + (size_t)CH * 98304;
  const size_t o_hs  = o_cs + 524288;
  const size_t o_cf  = o_hs + 33554432;

  ushort* Wx   = (ushort*)(ws + o_Wx);
  ushort* Rs   = (ushort*)(ws + o_Rs);
  float*  bp   = (float*)(ws + o_bp);
  ushort* zx0  = (ushort*)(ws + o_z0);
  ushort* zx1  = (ushort*)(ws + o_z1);
  u64*    hbc  = (u64*)(ws + o_hbc);
  float*  csv  = (float*)(ws + o_cs);
  ushort* hsv  = (ushort*)(ws + o_hs);
  float*  cfin = (float*)(ws + o_cf);

  pack_weights<<<256, 256, 0, stream>>>(Wf, Wi, Wg, Wo, Rf, Ri, Rg, Ro,
                                        bfp, bip, bgp, bop, Wx, Rs, bp);
  hipMemsetAsync(hbc, 0, 98304, stream);   // slot 0: h=0, tag=0 (fresh per call)

  // prologue: Zx for chunk 0 only
  fused_kernel<<<192, 512, 0, stream>>>(x, Wx, Rs, bp, zx1, zx0, hbc, csv,
                                        hsv, cfin, 0, CH, 0, 0);
  const int nch = 512 / CH;
  for (int c = 0; c < nch; ++c) {
    const ushort* zr = (c & 1) ? zx1 : zx0;
    ushort* zw       = (c & 1) ? zx0 : zx1;
    fused_kernel<<<192, 512, 0, stream>>>(x, Wx, Rs, bp, zr, zw, hbc, csv,
                                          hsv, cfin, c * CH, CH, (c + 1) * CH, 1);
  }
  reorder_kernel<<<dim3(512, 4), 256, 0, stream>>>(hsv, cfin, dout);
}

// Round 13
// 1713.271 us; speedup vs baseline: 1.1819x; 1.1819x over previous
//
#include <hip/hip_runtime.h>
#include <hip/hip_bf16.h>

typedef __attribute__((ext_vector_type(8))) short s16x8;
typedef __attribute__((ext_vector_type(4))) float f32x4;

__device__ __forceinline__ ushort f2bf(float x) {
  __hip_bfloat16 b = __float2bfloat16(x);
  return *reinterpret_cast<ushort*>(&b);
}
__device__ __forceinline__ float bf2f(ushort u) {
  union { unsigned int i; float f; } c; c.i = ((unsigned int)u) << 16; return c.f;
}
__device__ __forceinline__ float sigm_fast(float z) {
  return __builtin_amdgcn_rcpf(1.0f + __builtin_amdgcn_exp2f(z * -1.44269504088896f));
}

// ---------------------------------------------------------------------------
// K0: pack weights (validated R1-R12).
// ---------------------------------------------------------------------------
__global__ __launch_bounds__(256) void pack_weights(
    const float* __restrict__ Wf, const float* __restrict__ Wi,
    const float* __restrict__ Wg, const float* __restrict__ Wo,
    const float* __restrict__ Rf, const float* __restrict__ Ri,
    const float* __restrict__ Rg, const float* __restrict__ Ro,
    const float* __restrict__ bfp, const float* __restrict__ bip,
    const float* __restrict__ bgp, const float* __restrict__ bop,
    ushort* __restrict__ Wx, ushort* __restrict__ Rs, float* __restrict__ bp)
{
  const int p = blockIdx.x * 8 + (threadIdx.x >> 5);
  const int kk = (threadIdx.x & 31) * 16;
  const int gate = p & 3;
  const int hcol = (p >> 5) * 8 + ((p >> 4) & 1) * 4 + ((p & 15) >> 2);
  const float* W = (gate == 0) ? Wf : (gate == 1) ? Wi : (gate == 2) ? Wg : Wo;
  const float* R = (gate == 0) ? Rf : (gate == 1) ? Ri : (gate == 2) ? Rg : Ro;
  union { ushort u[16]; s16x8 v[2]; } wb, rb;
#pragma unroll
  for (int e = 0; e < 16; ++e) {
    const int k = kk + e;
    wb.u[e] = f2bf(W[(size_t)k * 512 + hcol]);
    rb.u[e] = f2bf(W[(size_t)(512 + k) * 512 + hcol] + R[(size_t)k * 512 + hcol]);
  }
  *(s16x8*)(Wx + (size_t)p * 512 + kk)     = wb.v[0];
  *(s16x8*)(Wx + (size_t)p * 512 + kk + 8) = wb.v[1];
  *(s16x8*)(Rs + (size_t)p * 512 + kk)     = rb.v[0];
  *(s16x8*)(Rs + (size_t)p * 512 + kk + 8) = rb.v[1];
  if ((threadIdx.x & 31) == 0) {
    const float* B = (gate == 0) ? bfp : (gate == 1) ? bip : (gate == 2) ? bgp : bop;
    bp[p] = B[hcol];
  }
}

// ---------------------------------------------------------------------------
// Fused kernel: grid = 160 WGs x 512 thr.
//   bid <  32: recurrence chunk [t0, t0+CH). Mapping: g = bid&3, mem = bid>>2.
//   bid >= 32: Zx GEMM for chunk [zxt0, zxt0+CH) -> zxw (bf16).
// Flags: one line per (g,mem), spread 4KB apart; deferred-flag protocol
// (vmcnt(0) -> barrier -> flag store) with publish stores last in vmem queue.
// Poll: lanes 0..7 only. This is the measured optimum (R7: 3.24 us/step);
// the per-step cost = ack + flag-visibility + h-load (3 agent-scope MALL
// RTTs) + work; all protocol alternatives measured slower (R3/4/6/8/9/10),
// and intra-XCD L2 sync is unreachable from HIP scopes (R11 null, R12 hang).
// ---------------------------------------------------------------------------
__global__ __launch_bounds__(512, 1) void fused_kernel(
    const float* __restrict__ x, const ushort* __restrict__ Wx,
    const ushort* __restrict__ Rs, const float* __restrict__ bp,
    const ushort* __restrict__ zxr, ushort* __restrict__ zxw,
    ushort* __restrict__ hbuf, float* __restrict__ csave,
    int* __restrict__ flags, ushort* __restrict__ hsave,
    float* __restrict__ cfinal, int t0, int CH, int zxt0, int do_rec)
{
  __shared__ ushort lds_u[33280];  // zx: [64][520]; rec: hsl(8192)+tbuf(1024)
  const int tid = threadIdx.x;
  const int wid = tid >> 6;
  const int lane = tid & 63;
  const int l15 = lane & 15;
  const int hi = lane >> 4;

  if (blockIdx.x >= 32) {
    // ================= Zx GEMM path (validated R5-R12) =================
    if (zxt0 >= 512) return;
    const int zbid = blockIdx.x - 32;
    const int pg = zbid & 15;
    const int ts = zbid >> 4;
    const int mpair = wid >> 2;
    const int np = wid & 3;
    const int q = pg * 4 + np;
    s16x8 Bg[2][16];
#pragma unroll
    for (int nt = 0; nt < 2; ++nt)
#pragma unroll
      for (int kc = 0; kc < 16; ++kc)
        Bg[nt][kc] = *(const s16x8*)(Wx + (size_t)(q * 32 + nt * 16 + l15) * 512 + kc * 32 + hi * 8);
    const int tper = CH >> 3;
    for (int tt = 0; tt < tper; ++tt) {
      const int tl = ts * tper + tt;
      const int t = zxt0 + tl;
      const float4* x4 = (const float4*)(x + (size_t)t * 32768);
#pragma unroll
      for (int j = 0; j < 16; ++j) {
        const int i4 = j * 512 + tid;
        const float4 v = x4[i4];
        const int row = i4 >> 7;
        const int c0 = (i4 & 127) * 4;
        ushort4 u;
        u.x = f2bf(v.x); u.y = f2bf(v.y); u.z = f2bf(v.z); u.w = f2bf(v.w);
        *(ushort4*)(&lds_u[row * 520 + c0]) = u;
      }
      __syncthreads();
#pragma unroll
      for (int a = 0; a < 2; ++a) {
        const int mt = mpair * 2 + a;
        f32x4 a0 = {0.f, 0.f, 0.f, 0.f};
        f32x4 a1 = {0.f, 0.f, 0.f, 0.f};
#pragma unroll
        for (int kc = 0; kc < 16; ++kc) {
          const s16x8 af = *(const s16x8*)(&lds_u[(mt * 16 + l15) * 520 + kc * 32 + hi * 8]);
          a0 = __builtin_amdgcn_mfma_f32_16x16x32_bf16(af, Bg[0][kc], a0, 0, 0, 0);
          a1 = __builtin_amdgcn_mfma_f32_16x16x32_bf16(af, Bg[1][kc], a1, 0, 0, 0);
        }
        union { ushort u[8]; s16x8 v; } ub;
#pragma unroll
        for (int r = 0; r < 4; ++r) { ub.u[r] = f2bf(a0[r]); ub.u[4 + r] = f2bf(a1[r]); }
        *(s16x8*)(zxw + ((((size_t)tl * 4 + mt) * 64 + q) * 64 + lane) * 8) = ub.v;
      }
      __syncthreads();
    }
    return;
  }

  // ================= recurrence path =================
  if (!do_rec) return;
  ushort* hsl = lds_u;           // 8192 ushorts, swizzled h tile
  ushort* tbuf = lds_u + 8192;   // 1024 ushorts, publish transpose
  const int bid = blockIdx.x;
  const int g = bid & 3;         // group 0..3 (16 batch rows)
  const int mem = bid >> 2;      // member 0..7
  const int q = mem * 8 + wid;   // packed col-group 0..63
  const int gate = lane & 3;

  // Rsum fragments: load once, pin (unified VGPR/AGPR file)
  f32x4 Brg[2][16];
#pragma unroll
  for (int nt = 0; nt < 2; ++nt)
#pragma unroll
    for (int kc = 0; kc < 16; ++kc) {
      Brg[nt][kc] = *(const f32x4*)(Rs + (size_t)(q * 32 + nt * 16 + l15) * 512 + kc * 32 + hi * 8);
      asm volatile("" : "+v"(Brg[nt][kc]));
    }
  const float b0 = bp[q * 32 + l15];
  const float b1 = bp[q * 32 + 16 + l15];

  float cst[2][4];
  float* csp = csave + ((size_t)(bid * 8 + wid) * 64 + lane) * 8;
  if (t0 == 0) {
#pragma unroll
    for (int i = 0; i < 2; ++i)
#pragma unroll
      for (int r = 0; r < 4; ++r) cst[i][r] = 0.0f;
  } else {
#pragma unroll
    for (int i = 0; i < 2; ++i)
#pragma unroll
      for (int r = 0; r < 4; ++r) cst[i][r] = csp[i * 4 + r];
  }

  const int srow = hi * 4 + gate;
  const int hcol0 = q * 8 + (l15 >> 2);
  const int crow = tid >> 5;
  const int cbyte = (tid & 31) * 32;
  const int cswz = (crow & 7) << 4;
  const int srcofs = crow * 512 + (cbyte >> 1);
  const int wofs0 = (crow * 1024 + (cbyte ^ cswz)) >> 1;
  const int wofs1 = (crow * 1024 + ((cbyte + 16) ^ cswz)) >> 1;
  const int abase = l15 * 1024 + hi * 16;
  const int aswz = (l15 & 7) << 4;
  // flags: 4KB-spread lines, one per (g,mem)
  int* const myflag = &flags[(g * 8 + mem) * 1024];
  int* const pollp = &flags[(g * 8 + (lane & 7)) * 1024];

  for (int tl = 0; tl < CH; ++tl) {
    const int t = t0 + tl;
    if (tl > 0) {
      // deferred flag: publish of slot tl was issued (last) in prev iteration
      asm volatile("s_waitcnt vmcnt(0)" ::: "memory");  // pub acks (queue tail)
      __syncthreads();                                  // all waves acked
      if (tid == 0)
        __hip_atomic_store(myflag, t, __ATOMIC_RELAXED, __HIP_MEMORY_SCOPE_AGENT);
    }
    // zx prefetch (issued before poll; arrives during poll/stage)
    const s16x8 zv = *(const s16x8*)(zxr + ((((size_t)tl * 4 + g) * 64 + q) * 64 + lane) * 8);
    if (tl > 0) {
      // poll: lanes 0..7 only
      int v = 0x7fffffff;
      if (lane < 8) v = __hip_atomic_load(pollp, __ATOMIC_RELAXED, __HIP_MEMORY_SCOPE_AGENT);
      while (!__all(v >= t)) {
        if (lane < 8) v = __hip_atomic_load(pollp, __ATOMIC_RELAXED, __HIP_MEMORY_SCOPE_AGENT);
      }
      asm volatile("" ::: "memory");
    }
    // h load + LDS stage (swizzled)
    const ushort* hs = hbuf + ((size_t)tl * 4 + g) * 8192;
    const s16x8 h0 = *(const s16x8*)(hs + srcofs);
    const s16x8 h1 = *(const s16x8*)(hs + srcofs + 8);
    *(s16x8*)(&hsl[wofs0]) = h0;
    *(s16x8*)(&hsl[wofs1]) = h1;
    __syncthreads();
    // z = h @ Rsum
    f32x4 a0 = {0.f, 0.f, 0.f, 0.f};
    f32x4 a1 = {0.f, 0.f, 0.f, 0.f};
#pragma unroll
    for (int kc = 0; kc < 16; ++kc) {
      const s16x8 af = *(const s16x8*)(&hsl[((abase + kc * 64) ^ aswz) >> 1]);
      a0 = __builtin_amdgcn_mfma_f32_16x16x32_bf16(af, __builtin_bit_cast(s16x8, Brg[0][kc]), a0, 0, 0, 0);
      a1 = __builtin_amdgcn_mfma_f32_16x16x32_bf16(af, __builtin_bit_cast(s16x8, Brg[1][kc]), a1, 0, 0, 0);
    }
    // gates + cell update
    float hv[2], cv[2];
#pragma unroll
    for (int nt = 0; nt < 2; ++nt) {
      float hr[4];
#pragma unroll
      for (int r = 0; r < 4; ++r) {
        float z = (nt ? a1[r] : a0[r]) + bf2f((ushort)zv[nt * 4 + r]) + (nt ? b1 : b0);
        const float zz = (gate == 2) ? z + z : z;
        const float s = sigm_fast(zz);
        const float act = (gate == 2) ? (s + s - 1.0f) : s;
        const int ai = __float_as_int(act);
        const float fv = __int_as_float(__builtin_amdgcn_mov_dpp(ai, 0x00, 0xF, 0xF, true));
        const float iv = __int_as_float(__builtin_amdgcn_mov_dpp(ai, 0x55, 0xF, 0xF, true));
        const float gv = __int_as_float(__builtin_amdgcn_mov_dpp(ai, 0xAA, 0xF, 0xF, true));
        const float ov = __int_as_float(__builtin_amdgcn_mov_dpp(ai, 0xFF, 0xF, 0xF, true));
        const float cn = fmaf(fv, cst[nt][r], iv * gv);
        cst[nt][r] = cn;
        const float s2 = sigm_fast(cn + cn);
        hr[r] = ov * (s2 + s2 - 1.0f);
      }
      hv[nt] = (gate == 0) ? hr[0] : (gate == 1) ? hr[1] : (gate == 2) ? hr[2] : hr[3];
      cv[nt] = (gate == 0) ? cst[nt][0] : (gate == 1) ? cst[nt][1]
             : (gate == 2) ? cst[nt][2] : cst[nt][3];
    }
    const ushort pb0 = f2bf(hv[0]), pb1 = f2bf(hv[1]);
    // --- archive first (so publish stores are LAST in the vmem queue) ---
    {
      ushort2 hp; hp.x = pb0; hp.y = pb1;
      *(ushort2*)(hsave + (((size_t)t * 4 + g) * 8 + mem) * 1024 + wid * 128 + lane * 2) = hp;
      if (t == 511) {
        float* cf = cfinal + (((size_t)(g * 8 + mem) * 8 + wid) * 64 + lane) * 2;
        cf[0] = cv[0]; cf[1] = cv[1];
      }
    }
    // --- publish via per-wave LDS transpose ---
    tbuf[wid * 128 + srow * 8 + (l15 >> 2)]     = pb0;
    tbuf[wid * 128 + srow * 8 + (l15 >> 2) + 4] = pb1;
    asm volatile("s_waitcnt lgkmcnt(0)" ::: "memory");
    __builtin_amdgcn_sched_barrier(0);
    if (tl != CH - 1) {
      if (lane < 16) {
        const unsigned long long* rp = (const unsigned long long*)&tbuf[wid * 128 + lane * 8];
        ushort* dst = hbuf + ((size_t)(tl + 1) * 4 + g) * 8192 + lane * 512 + q * 8;
        __hip_atomic_store((unsigned long long*)dst, rp[0],
                           __ATOMIC_RELAXED, __HIP_MEMORY_SCOPE_AGENT);
        __hip_atomic_store((unsigned long long*)(dst + 4), rp[1],
                           __ATOMIC_RELAXED, __HIP_MEMORY_SCOPE_AGENT);
      }
    } else {
      // chunk handoff into slot 0 (kernel boundary publishes it)
      ushort* hn0 = hbuf + (size_t)g * 8192;
      hn0[srow * 512 + hcol0]     = pb0;
      hn0[srow * 512 + hcol0 + 4] = pb1;
    }
  }
#pragma unroll
  for (int i = 0; i < 2; ++i)
#pragma unroll
    for (int r = 0; r < 4; ++r) csp[i * 4 + r] = cst[i][r];
}

// ---------------------------------------------------------------------------
// Reorder: hsave/cfinal -> dout (validated R5-R12).
// ---------------------------------------------------------------------------
__global__ __launch_bounds__(256) void reorder_kernel(
    const ushort* __restrict__ hsave, const float* __restrict__ cfinal,
    float* __restrict__ dout)
{
  __shared__ ushort lds[8192];
  const int t = blockIdx.x;
  const int g = blockIdx.y;
  const int tid = threadIdx.x;
  const s16x8* src = (const s16x8*)(hsave + ((size_t)t * 4 + g) * 8192);
#pragma unroll
  for (int j = 0; j < 4; ++j) {
    const int i = j * 256 + tid;
    *(s16x8*)(&lds[i * 8]) = src[i];
  }
  __syncthreads();
  const int srow = tid >> 4;
  const int cb = (tid & 15) * 32;
  float buf[32];
#pragma unroll
  for (int cc = 0; cc < 32; ++cc) {
    const int col = cb + cc;
    const int q = col >> 3;
    const int memb = q >> 3;
    const int wd = q & 7;
    const int nt = (col >> 2) & 1;
    const int l15v = ((col & 3) << 2) | (srow & 3);
    const int lanev = ((srow >> 2) << 4) | l15v;
    buf[cc] = bf2f(lds[memb * 1024 + wd * 128 + lanev * 2 + nt]);
  }
  float* o = dout + (size_t)t * 32768 + (size_t)(g * 16 + srow) * 512 + cb;
#pragma unroll
  for (int j = 0; j < 8; ++j) *(float4*)(o + j * 4) = *(const float4*)(&buf[j * 4]);
  if (t == 511) {
    float* oh = dout + (size_t)16777216 + (size_t)(g * 16 + srow) * 512 + cb;
#pragma unroll
    for (int j = 0; j < 8; ++j) *(float4*)(oh + j * 4) = *(const float4*)(&buf[j * 4]);
    float cbuf[32];
#pragma unroll
    for (int cc = 0; cc < 32; ++cc) {
      const int col = cb + cc;
      const int q = col >> 3;
      const int memb = q >> 3;
      const int wd = q & 7;
      const int nt = (col >> 2) & 1;
      const int l15v = ((col & 3) << 2) | (srow & 3);
      const int lanev = ((srow >> 2) << 4) | l15v;
      cbuf[cc] = cfinal[(((size_t)(g * 8 + memb) * 8 + wd) * 64 + lanev) * 2 + nt];
    }
    float* oc = dout + (size_t)16809984 + (size_t)(g * 16 + srow) * 512 + cb;
#pragma unroll
    for (int j = 0; j < 8; ++j) *(float4*)(oc + j * 4) = *(const float4*)(&cbuf[j * 4]);
  }
}

// ---------------------------------------------------------------------------
extern "C" void kernel_launch(void* const* d_in, const int* in_sizes, int n_in,
                              void* d_out, int out_size, void* d_ws, size_t ws_size,
                              hipStream_t stream)
{
  const float* x   = (const float*)d_in[0];
  const float* Wf  = (const float*)d_in[1];
  const float* bfp = (const float*)d_in[2];
  const float* Wi  = (const float*)d_in[3];
  const float* bip = (const float*)d_in[4];
  const float* Wg  = (const float*)d_in[5];
  const float* bgp = (const float*)d_in[6];
  const float* Wo  = (const float*)d_in[7];
  const float* bop = (const float*)d_in[8];
  const float* Rf  = (const float*)d_in[9];
  const float* Ri  = (const float*)d_in[10];
  const float* Rg  = (const float*)d_in[11];
  const float* Ro  = (const float*)d_in[12];
  float* dout = (float*)d_out;
  char* ws = (char*)d_ws;

  const size_t o_Wx = 0;
  const size_t o_Rs = 2097152;
  const size_t o_bp = 4194304;
  const size_t o_z0 = o_bp + 8192;

  int CH = 64;
  for (;;) {
    const size_t need = o_z0 + 2 * (size_t)CH * 262144          // zx dbuf
                      + (size_t)(CH + 1) * 65536                // hbuf slots
                      + 524288 + 131072 + 33554432 + 131072;    // cs, fl, hs, cf
    if (need <= ws_size || CH <= 8) break;
    CH >>= 1;
  }
  const size_t zsz  = (size_t)CH * 262144;
  const size_t o_z1 = o_z0 + zsz;
  const size_t o_hb = o_z1 + zsz;
  const size_t o_cs = o_hb + (size_t)(CH + 1) * 65536;
  const size_t o_fl = o_cs + 524288;
  const size_t o_hs = o_fl + 131072;
  const size_t o_cf = o_hs + 33554432;

  ushort* Wx   = (ushort*)(ws + o_Wx);
  ushort* Rs   = (ushort*)(ws + o_Rs);
  float*  bp   = (float*)(ws + o_bp);
  ushort* zx0  = (ushort*)(ws + o_z0);
  ushort* zx1  = (ushort*)(ws + o_z1);
  ushort* hb   = (ushort*)(ws + o_hb);
  float*  csv  = (float*)(ws + o_cs);
  int*    fl   = (int*)(ws + o_fl);
  ushort* hsv  = (ushort*)(ws + o_hs);
  float*  cfin = (float*)(ws + o_cf);

  pack_weights<<<256, 256, 0, stream>>>(Wf, Wi, Wg, Wo, Rf, Ri, Rg, Ro,
                                        bfp, bip, bgp, bop, Wx, Rs, bp);
  hipMemsetAsync(hb, 0, 65536, stream);   // h(0) = 0 (slot 0, all groups)
  hipMemsetAsync(fl, 0, 131072, stream);  // flag lines (monotone per call)

  // prologue: Zx for chunk 0 only
  fused_kernel<<<160, 512, 0, stream>>>(x, Wx, Rs, bp, zx1, zx0, hb, csv, fl,
                                        hsv, cfin, 0, CH, 0, 0);
  const int nch = 512 / CH;
  for (int c = 0; c < nch; ++c) {
    const ushort* zr = (c & 1) ? zx1 : zx0;
    ushort* zw       = (c & 1) ? zx0 : zx1;
    fused_kernel<<<160, 512, 0, stream>>>(x, Wx, Rs, bp, zr, zw, hb, csv, fl,
                                          hsv, cfin, c * CH, CH, (c + 1) * CH, 1);
  }
  reorder_kernel<<<dim3(512, 4), 256, 0, stream>>>(hsv, cfin, dout);
}

// Round 14
// 1703.574 us; speedup vs baseline: 1.1887x; 1.0057x over previous
//
#include <hip/hip_runtime.h>
#include <hip/hip_bf16.h>

typedef __attribute__((ext_vector_type(8))) short s16x8;
typedef __attribute__((ext_vector_type(4))) float f32x4;

__device__ __forceinline__ ushort f2bf(float x) {
  __hip_bfloat16 b = __float2bfloat16(x);
  return *reinterpret_cast<ushort*>(&b);
}
__device__ __forceinline__ float bf2f(ushort u) {
  union { unsigned int i; float f; } c; c.i = ((unsigned int)u) << 16; return c.f;
}
__device__ __forceinline__ float sigm_fast(float z) {
  return __builtin_amdgcn_rcpf(1.0f + __builtin_amdgcn_exp2f(z * -1.44269504088896f));
}

// ---------------------------------------------------------------------------
// K0: pack weights, coalesced rewrite.
// Identity discovered: hcol(p) = (p - gate)/4, i.e. p = 4*h + gate.
//   Wx[4h+g][k] = bf16(W_g[k][h])                      (k in [0,512))
//   Rs[4h+g][k] = bf16(W_g[512+k][h] + R_g[k][h])
//   bp[4h+g]    = B_g[h]
// Grid 128 WGs x 256 thr: gate = bid&3, half = (bid>>2)&1, kb = bid>>3.
// Phase 1: coalesced float4 row reads -> bf16 -> LDS [32][516] (k-major).
// Phase 2: per packed col, 64B contiguous k-run to global.
// ---------------------------------------------------------------------------
__global__ __launch_bounds__(256) void pack_weights(
    const float* __restrict__ Wf, const float* __restrict__ Wi,
    const float* __restrict__ Wg, const float* __restrict__ Wo,
    const float* __restrict__ Rf, const float* __restrict__ Ri,
    const float* __restrict__ Rg, const float* __restrict__ Ro,
    const float* __restrict__ bfp, const float* __restrict__ bip,
    const float* __restrict__ bgp, const float* __restrict__ bop,
    ushort* __restrict__ Wx, ushort* __restrict__ Rs, float* __restrict__ bp)
{
  __shared__ ushort ld[32 * 516];  // [krow][hcol], pad 512->516
  const int bid = blockIdx.x;
  const int gate = bid & 3;
  const int half = (bid >> 2) & 1;
  const int kb = bid >> 3;               // 0..15
  const int tid = threadIdx.x;
  const float* W = (gate == 0) ? Wf : (gate == 1) ? Wi : (gate == 2) ? Wg : Wo;
  const float* R = (gate == 0) ? Rf : (gate == 1) ? Ri : (gate == 2) ? Rg : Ro;

  const int krow = tid >> 3;             // 0..31
  const int seg = tid & 7;
  const int klocal = kb * 32 + krow;     // 0..511
  const float* srcW = W + (size_t)(half ? 512 + klocal : klocal) * 512;
  const float* srcR = R + (size_t)klocal * 512;
#pragma unroll
  for (int i = 0; i < 16; ++i) {
    const int col = seg * 4 + i * 32;    // coalesced across seg
    float4 v = *(const float4*)(srcW + col);
    if (half) {
      const float4 r = *(const float4*)(srcR + col);
      v.x += r.x; v.y += r.y; v.z += r.z; v.w += r.w;
    }
    ushort4 u;
    u.x = f2bf(v.x); u.y = f2bf(v.y); u.z = f2bf(v.z); u.w = f2bf(v.w);
    *(ushort4*)(&ld[krow * 516 + col]) = u;
  }
  __syncthreads();

  ushort* out = half ? Rs : Wx;
#pragma unroll
  for (int j = 0; j < 2; ++j) {
    const int m = tid * 2 + j;           // hcol 0..511
    const int p = m * 4 + gate;
    union { ushort u[32]; s16x8 v[4]; } buf;
#pragma unroll
    for (int kk = 0; kk < 32; ++kk) buf.u[kk] = ld[kk * 516 + m];
    s16x8* d = (s16x8*)(out + (size_t)p * 512 + kb * 32);
    d[0] = buf.v[0]; d[1] = buf.v[1]; d[2] = buf.v[2]; d[3] = buf.v[3];
  }
  if (half == 0 && kb == 0) {
    const float* B = (gate == 0) ? bfp : (gate == 1) ? bip : (gate == 2) ? bgp : bop;
#pragma unroll
    for (int j = 0; j < 2; ++j) {
      const int m = tid * 2 + j;
      bp[m * 4 + gate] = B[m];
    }
  }
}

// ---------------------------------------------------------------------------
// Fused kernel: grid = 160 WGs x 512 thr (validated R7/R13 optimum).
//   bid <  32: recurrence chunk [t0, t0+CH). Mapping: g = bid&3, mem = bid>>2.
//   bid >= 32: Zx GEMM for chunk [zxt0, zxt0+CH) -> zxw (bf16).
// Flags: one line per (g,mem), spread 4KB apart; deferred-flag protocol
// (vmcnt(0) -> barrier -> flag store) with publish stores last in vmem queue.
// Poll: lanes 0..7 only. Per-step cost = ack + flag-visibility + h-load
// (~3.5 agent-scope MALL RTTs) + work; all protocol alternatives measured
// slower (R3/4/6/8/9/10), intra-XCD L2 sync unreachable from HIP (R11/R12).
// ---------------------------------------------------------------------------
__global__ __launch_bounds__(512, 1) void fused_kernel(
    const float* __restrict__ x, const ushort* __restrict__ Wx,
    const ushort* __restrict__ Rs, const float* __restrict__ bp,
    const ushort* __restrict__ zxr, ushort* __restrict__ zxw,
    ushort* __restrict__ hbuf, float* __restrict__ csave,
    int* __restrict__ flags, ushort* __restrict__ hsave,
    float* __restrict__ cfinal, int t0, int CH, int zxt0, int do_rec)
{
  __shared__ ushort lds_u[33280];  // zx: [64][520]; rec: hsl(8192)+tbuf(1024)
  const int tid = threadIdx.x;
  const int wid = tid >> 6;
  const int lane = tid & 63;
  const int l15 = lane & 15;
  const int hi = lane >> 4;

  if (blockIdx.x >= 32) {
    // ================= Zx GEMM path (validated R5-R13) =================
    if (zxt0 >= 512) return;
    const int zbid = blockIdx.x - 32;
    const int pg = zbid & 15;
    const int ts = zbid >> 4;
    const int mpair = wid >> 2;
    const int np = wid & 3;
    const int q = pg * 4 + np;
    s16x8 Bg[2][16];
#pragma unroll
    for (int nt = 0; nt < 2; ++nt)
#pragma unroll
      for (int kc = 0; kc < 16; ++kc)
        Bg[nt][kc] = *(const s16x8*)(Wx + (size_t)(q * 32 + nt * 16 + l15) * 512 + kc * 32 + hi * 8);
    const int tper = CH >> 3;
    for (int tt = 0; tt < tper; ++tt) {
      const int tl = ts * tper + tt;
      const int t = zxt0 + tl;
      const float4* x4 = (const float4*)(x + (size_t)t * 32768);
#pragma unroll
      for (int j = 0; j < 16; ++j) {
        const int i4 = j * 512 + tid;
        const float4 v = x4[i4];
        const int row = i4 >> 7;
        const int c0 = (i4 & 127) * 4;
        ushort4 u;
        u.x = f2bf(v.x); u.y = f2bf(v.y); u.z = f2bf(v.z); u.w = f2bf(v.w);
        *(ushort4*)(&lds_u[row * 520 + c0]) = u;
      }
      __syncthreads();
#pragma unroll
      for (int a = 0; a < 2; ++a) {
        const int mt = mpair * 2 + a;
        f32x4 a0 = {0.f, 0.f, 0.f, 0.f};
        f32x4 a1 = {0.f, 0.f, 0.f, 0.f};
#pragma unroll
        for (int kc = 0; kc < 16; ++kc) {
          const s16x8 af = *(const s16x8*)(&lds_u[(mt * 16 + l15) * 520 + kc * 32 + hi * 8]);
          a0 = __builtin_amdgcn_mfma_f32_16x16x32_bf16(af, Bg[0][kc], a0, 0, 0, 0);
          a1 = __builtin_amdgcn_mfma_f32_16x16x32_bf16(af, Bg[1][kc], a1, 0, 0, 0);
        }
        union { ushort u[8]; s16x8 v; } ub;
#pragma unroll
        for (int r = 0; r < 4; ++r) { ub.u[r] = f2bf(a0[r]); ub.u[4 + r] = f2bf(a1[r]); }
        *(s16x8*)(zxw + ((((size_t)tl * 4 + mt) * 64 + q) * 64 + lane) * 8) = ub.v;
      }
      __syncthreads();
    }
    return;
  }

  // ================= recurrence path =================
  if (!do_rec) return;
  ushort* hsl = lds_u;           // 8192 ushorts, swizzled h tile
  ushort* tbuf = lds_u + 8192;   // 1024 ushorts, publish transpose
  const int bid = blockIdx.x;
  const int g = bid & 3;         // group 0..3 (16 batch rows)
  const int mem = bid >> 2;      // member 0..7
  const int q = mem * 8 + wid;   // packed col-group 0..63
  const int gate = lane & 3;

  // Rsum fragments: load once, pin (unified VGPR/AGPR file)
  f32x4 Brg[2][16];
#pragma unroll
  for (int nt = 0; nt < 2; ++nt)
#pragma unroll
    for (int kc = 0; kc < 16; ++kc) {
      Brg[nt][kc] = *(const f32x4*)(Rs + (size_t)(q * 32 + nt * 16 + l15) * 512 + kc * 32 + hi * 8);
      asm volatile("" : "+v"(Brg[nt][kc]));
    }
  const float b0 = bp[q * 32 + l15];
  const float b1 = bp[q * 32 + 16 + l15];

  float cst[2][4];
  float* csp = csave + ((size_t)(bid * 8 + wid) * 64 + lane) * 8;
  if (t0 == 0) {
#pragma unroll
    for (int i = 0; i < 2; ++i)
#pragma unroll
      for (int r = 0; r < 4; ++r) cst[i][r] = 0.0f;
  } else {
#pragma unroll
    for (int i = 0; i < 2; ++i)
#pragma unroll
      for (int r = 0; r < 4; ++r) cst[i][r] = csp[i * 4 + r];
  }

  const int srow = hi * 4 + gate;
  const int hcol0 = q * 8 + (l15 >> 2);
  const int crow = tid >> 5;
  const int cbyte = (tid & 31) * 32;
  const int cswz = (crow & 7) << 4;
  const int srcofs = crow * 512 + (cbyte >> 1);
  const int wofs0 = (crow * 1024 + (cbyte ^ cswz)) >> 1;
  const int wofs1 = (crow * 1024 + ((cbyte + 16) ^ cswz)) >> 1;
  const int abase = l15 * 1024 + hi * 16;
  const int aswz = (l15 & 7) << 4;
  // flags: 4KB-spread lines, one per (g,mem)
  int* const myflag = &flags[(g * 8 + mem) * 1024];
  int* const pollp = &flags[(g * 8 + (lane & 7)) * 1024];

  for (int tl = 0; tl < CH; ++tl) {
    const int t = t0 + tl;
    if (tl > 0) {
      // deferred flag: publish of slot tl was issued (last) in prev iteration
      asm volatile("s_waitcnt vmcnt(0)" ::: "memory");  // pub acks (queue tail)
      __syncthreads();                                  // all waves acked
      if (tid == 0)
        __hip_atomic_store(myflag, t, __ATOMIC_RELAXED, __HIP_MEMORY_SCOPE_AGENT);
    }
    // zx prefetch (issued before poll; arrives during poll/stage)
    const s16x8 zv = *(const s16x8*)(zxr + ((((size_t)tl * 4 + g) * 64 + q) * 64 + lane) * 8);
    if (tl > 0) {
      // poll: lanes 0..7 only
      int v = 0x7fffffff;
      if (lane < 8) v = __hip_atomic_load(pollp, __ATOMIC_RELAXED, __HIP_MEMORY_SCOPE_AGENT);
      while (!__all(v >= t)) {
        if (lane < 8) v = __hip_atomic_load(pollp, __ATOMIC_RELAXED, __HIP_MEMORY_SCOPE_AGENT);
      }
      asm volatile("" ::: "memory");
    }
    // h load + LDS stage (swizzled)
    const ushort* hs = hbuf + ((size_t)tl * 4 + g) * 8192;
    const s16x8 h0 = *(const s16x8*)(hs + srcofs);
    const s16x8 h1 = *(const s16x8*)(hs + srcofs + 8);
    *(s16x8*)(&hsl[wofs0]) = h0;
    *(s16x8*)(&hsl[wofs1]) = h1;
    __syncthreads();
    // z = h @ Rsum
    f32x4 a0 = {0.f, 0.f, 0.f, 0.f};
    f32x4 a1 = {0.f, 0.f, 0.f, 0.f};
#pragma unroll
    for (int kc = 0; kc < 16; ++kc) {
      const s16x8 af = *(const s16x8*)(&hsl[((abase + kc * 64) ^ aswz) >> 1]);
      a0 = __builtin_amdgcn_mfma_f32_16x16x32_bf16(af, __builtin_bit_cast(s16x8, Brg[0][kc]), a0, 0, 0, 0);
      a1 = __builtin_amdgcn_mfma_f32_16x16x32_bf16(af, __builtin_bit_cast(s16x8, Brg[1][kc]), a1, 0, 0, 0);
    }
    // gates + cell update
    float hv[2], cv[2];
#pragma unroll
    for (int nt = 0; nt < 2; ++nt) {
      float hr[4];
#pragma unroll
      for (int r = 0; r < 4; ++r) {
        float z = (nt ? a1[r] : a0[r]) + bf2f((ushort)zv[nt * 4 + r]) + (nt ? b1 : b0);
        const float zz = (gate == 2) ? z + z : z;
        const float s = sigm_fast(zz);
        const float act = (gate == 2) ? (s + s - 1.0f) : s;
        const int ai = __float_as_int(act);
        const float fv = __int_as_float(__builtin_amdgcn_mov_dpp(ai, 0x00, 0xF, 0xF, true));
        const float iv = __int_as_float(__builtin_amdgcn_mov_dpp(ai, 0x55, 0xF, 0xF, true));
        const float gv = __int_as_float(__builtin_amdgcn_mov_dpp(ai, 0xAA, 0xF, 0xF, true));
        const float ov = __int_as_float(__builtin_amdgcn_mov_dpp(ai, 0xFF, 0xF, 0xF, true));
        const float cn = fmaf(fv, cst[nt][r], iv * gv);
        cst[nt][r] = cn;
        const float s2 = sigm_fast(cn + cn);
        hr[r] = ov * (s2 + s2 - 1.0f);
      }
      hv[nt] = (gate == 0) ? hr[0] : (gate == 1) ? hr[1] : (gate == 2) ? hr[2] : hr[3];
      cv[nt] = (gate == 0) ? cst[nt][0] : (gate == 1) ? cst[nt][1]
             : (gate == 2) ? cst[nt][2] : cst[nt][3];
    }
    const ushort pb0 = f2bf(hv[0]), pb1 = f2bf(hv[1]);
    // --- archive first (so publish stores are LAST in the vmem queue) ---
    {
      ushort2 hp; hp.x = pb0; hp.y = pb1;
      *(ushort2*)(hsave + (((size_t)t * 4 + g) * 8 + mem) * 1024 + wid * 128 + lane * 2) = hp;
      if (t == 511) {
        float* cf = cfinal + (((size_t)(g * 8 + mem) * 8 + wid) * 64 + lane) * 2;
        cf[0] = cv[0]; cf[1] = cv[1];
      }
    }
    // --- publish via per-wave LDS transpose ---
    tbuf[wid * 128 + srow * 8 + (l15 >> 2)]     = pb0;
    tbuf[wid * 128 + srow * 8 + (l15 >> 2) + 4] = pb1;
    asm volatile("s_waitcnt lgkmcnt(0)" ::: "memory");
    __builtin_amdgcn_sched_barrier(0);
    if (tl != CH - 1) {
      if (lane < 16) {
        const unsigned long long* rp = (const unsigned long long*)&tbuf[wid * 128 + lane * 8];
        ushort* dst = hbuf + ((size_t)(tl + 1) * 4 + g) * 8192 + lane * 512 + q * 8;
        __hip_atomic_store((unsigned long long*)dst, rp[0],
                           __ATOMIC_RELAXED, __HIP_MEMORY_SCOPE_AGENT);
        __hip_atomic_store((unsigned long long*)(dst + 4), rp[1],
                           __ATOMIC_RELAXED, __HIP_MEMORY_SCOPE_AGENT);
      }
    } else {
      // chunk handoff into slot 0 (kernel boundary publishes it)
      ushort* hn0 = hbuf + (size_t)g * 8192;
      hn0[srow * 512 + hcol0]     = pb0;
      hn0[srow * 512 + hcol0 + 4] = pb1;
    }
  }
#pragma unroll
  for (int i = 0; i < 2; ++i)
#pragma unroll
    for (int r = 0; r < 4; ++r) csp[i * 4 + r] = cst[i][r];
}

// ---------------------------------------------------------------------------
// Reorder: hsave/cfinal -> dout (validated R5-R13).
// ---------------------------------------------------------------------------
__global__ __launch_bounds__(256) void reorder_kernel(
    const ushort* __restrict__ hsave, const float* __restrict__ cfinal,
    float* __restrict__ dout)
{
  __shared__ ushort lds[8192];
  const int t = blockIdx.x;
  const int g = blockIdx.y;
  const int tid = threadIdx.x;
  const s16x8* src = (const s16x8*)(hsave + ((size_t)t * 4 + g) * 8192);
#pragma unroll
  for (int j = 0; j < 4; ++j) {
    const int i = j * 256 + tid;
    *(s16x8*)(&lds[i * 8]) = src[i];
  }
  __syncthreads();
  const int srow = tid >> 4;
  const int cb = (tid & 15) * 32;
  float buf[32];
#pragma unroll
  for (int cc = 0; cc < 32; ++cc) {
    const int col = cb + cc;
    const int q = col >> 3;
    const int memb = q >> 3;
    const int wd = q & 7;
    const int nt = (col >> 2) & 1;
    const int l15v = ((col & 3) << 2) | (srow & 3);
    const int lanev = ((srow >> 2) << 4) | l15v;
    buf[cc] = bf2f(lds[memb * 1024 + wd * 128 + lanev * 2 + nt]);
  }
  float* o = dout + (size_t)t * 32768 + (size_t)(g * 16 + srow) * 512 + cb;
#pragma unroll
  for (int j = 0; j < 8; ++j) *(float4*)(o + j * 4) = *(const float4*)(&buf[j * 4]);
  if (t == 511) {
    float* oh = dout + (size_t)16777216 + (size_t)(g * 16 + srow) * 512 + cb;
#pragma unroll
    for (int j = 0; j < 8; ++j) *(float4*)(oh + j * 4) = *(const float4*)(&buf[j * 4]);
    float cbuf[32];
#pragma unroll
    for (int cc = 0; cc < 32; ++cc) {
      const int col = cb + cc;
      const int q = col >> 3;
      const int memb = q >> 3;
      const int wd = q & 7;
      const int nt = (col >> 2) & 1;
      const int l15v = ((col & 3) << 2) | (srow & 3);
      const int lanev = ((srow >> 2) << 4) | l15v;
      cbuf[cc] = cfinal[(((size_t)(g * 8 + memb) * 8 + wd) * 64 + lanev) * 2 + nt];
    }
    float* oc = dout + (size_t)16809984 + (size_t)(g * 16 + srow) * 512 + cb;
#pragma unroll
    for (int j = 0; j < 8; ++j) *(float4*)(oc + j * 4) = *(const float4*)(&cbuf[j * 4]);
  }
}

// ---------------------------------------------------------------------------
extern "C" void kernel_launch(void* const* d_in, const int* in_sizes, int n_in,
                              void* d_out, int out_size, void* d_ws, size_t ws_size,
                              hipStream_t stream)
{
  const float* x   = (const float*)d_in[0];
  const float* Wf  = (const float*)d_in[1];
  const float* bfp = (const float*)d_in[2];
  const float* Wi  = (const float*)d_in[3];
  const float* bip = (const float*)d_in[4];
  const float* Wg  = (const float*)d_in[5];
  const float* bgp = (const float*)d_in[6];
  const float* Wo  = (const float*)d_in[7];
  const float* bop = (const float*)d_in[8];
  const float* Rf  = (const float*)d_in[9];
  const float* Ri  = (const float*)d_in[10];
  const float* Rg  = (const float*)d_in[11];
  const float* Ro  = (const float*)d_in[12];
  float* dout = (float*)d_out;
  char* ws = (char*)d_ws;

  const size_t o_Wx = 0;
  const size_t o_Rs = 2097152;
  const size_t o_bp = 4194304;
  const size_t o_z0 = o_bp + 8192;

  int CH = 64;
  for (;;) {
    const size_t need = o_z0 + 2 * (size_t)CH * 262144          // zx dbuf
                      + (size_t)(CH + 1) * 65536                // hbuf slots
                      + 524288 + 131072 + 33554432 + 131072;    // cs, fl, hs, cf
    if (need <= ws_size || CH <= 8) break;
    CH >>= 1;
  }
  const size_t zsz  = (size_t)CH * 262144;
  const size_t o_z1 = o_z0 + zsz;
  const size_t o_hb = o_z1 + zsz;
  const size_t o_cs = o_hb + (size_t)(CH + 1) * 65536;
  const size_t o_fl = o_cs + 524288;
  const size_t o_hs = o_fl + 131072;
  const size_t o_cf = o_hs + 33554432;

  ushort* Wx   = (ushort*)(ws + o_Wx);
  ushort* Rs   = (ushort*)(ws + o_Rs);
  float*  bp   = (float*)(ws + o_bp);
  ushort* zx0  = (ushort*)(ws + o_z0);
  ushort* zx1  = (ushort*)(ws + o_z1);
  ushort* hb   = (ushort*)(ws + o_hb);
  float*  csv  = (float*)(ws + o_cs);
  int*    fl   = (int*)(ws + o_fl);
  ushort* hsv  = (ushort*)(ws + o_hs);
  float*  cfin = (float*)(ws + o_cf);

  pack_weights<<<128, 256, 0, stream>>>(Wf, Wi, Wg, Wo, Rf, Ri, Rg, Ro,
                                        bfp, bip, bgp, bop, Wx, Rs, bp);
  hipMemsetAsync(hb, 0, 65536, stream);   // h(0) = 0 (slot 0, all groups)
  hipMemsetAsync(fl, 0, 131072, stream);  // flag lines (monotone per call)

  // prologue: Zx for chunk 0 only
  fused_kernel<<<160, 512, 0, stream>>>(x, Wx, Rs, bp, zx1, zx0, hb, csv, fl,
                                        hsv, cfin, 0, CH, 0, 0);
  const int nch = 512 / CH;
  for (int c = 0; c < nch; ++c) {
    const ushort* zr = (c & 1) ? zx1 : zx0;
    ushort* zw       = (c & 1) ? zx0 : zx1;
    fused_kernel<<<160, 512, 0, stream>>>(x, Wx, Rs, bp, zr, zw, hb, csv, fl,
                                          hsv, cfin, c * CH, CH, (c + 1) * CH, 1);
  }
  reorder_kernel<<<dim3(512, 4), 256, 0, stream>>>(hsv, cfin, dout);
}